// Round 10
// baseline (580.076 us; speedup 1.0000x reference)
//
#include <hip/hip_runtime.h>
#include <hip/hip_bf16.h>
#include <math.h>

// SkipGRU on MI355X, round 10: row-ownership chain — zero cross-WG coupling.
// r5-r9 evidence: graph-node overhead ~4-5us (12 nodes), cross-WG barrier
// ~13us/step regardless of implementation (r6/r7/r8: 109/154/110us chains).
// Fix: each WG owns 16 COMPLETE rows of h (all 512 cols) -> h never leaves
// the WG; all 8 steps run in one kernel with only __syncthreads. 16
// independent WGs (1 full MFMA M-tile each, no padding). Graph: 3 nodes
// (fused prologue, gemm_mx, chain).
//
// Only chain j=23 contributes to outputs[:, -1, :] (t=191 = chunk 7 lane 23):
// 8 sequential GRU steps over x[:, c*24+23, :], h[256,512].
//
// mfma_f32_16x16x32_bf16 layouts (learn_hip m89-verified, r4-r9 validated):
//   A: lane l holds A[l&15][(l>>4)*8 + j]
//   B: lane l holds B[(l>>4)*8 + j][l&15]  (B^T row-major -> contiguous load)
//   D: lane l reg q -> row (l>>4)*4+q, col l&15
//
// h LDS tile [16 rows][512 bf16] = 16KB, XOR-swizzled: byte-in-row offset
// off -> off ^ ((row&7)<<4), applied identically on write and read
// (bijection per row; spreads the 1024B row stride across banks, G4 recipe).

typedef float f32x4 __attribute__((ext_vector_type(4)));
typedef short short8 __attribute__((ext_vector_type(8)));

#define BB 256
#define UU 512
#define KK 512
#define N3 1536

__device__ __forceinline__ float sigmoidf_(float s) {
    return 1.0f / (1.0f + __expf(-s));
}

// Fused prologue: blocks [0,768) transpose ker, [768,1536) transpose rker,
// [1536,2048) gather+convert x. All 256-thread blocks, branch block-uniform.
__global__ __launch_bounds__(256)
void prologue(const float* __restrict__ ker, const float* __restrict__ rker,
              const float* __restrict__ x,
              __hip_bfloat16* __restrict__ Kt, __hip_bfloat16* __restrict__ Rtb,
              __hip_bfloat16* __restrict__ Xb)
{
    __shared__ float tile[32][33];
    const int blk = blockIdx.x;
    const int tid = threadIdx.x;
    if (blk < 1536) {
        const float* W = (blk < 768) ? ker : rker;
        __hip_bfloat16* Wt = (blk < 768) ? Kt : Rtb;
        const int b = (blk < 768) ? blk : blk - 768;
        const int xx = tid & 31, yy = tid >> 5;           // (32, 8)
        const int c0 = (b % 48) * 32;                     // C = 1536
        const int r0 = (b / 48) * 32;                     // R = 512
        #pragma unroll
        for (int i = 0; i < 32; i += 8)
            tile[yy + i][xx] = W[(long)(r0 + yy + i) * N3 + c0 + xx];
        __syncthreads();
        #pragma unroll
        for (int i = 0; i < 32; i += 8)
            Wt[(long)(c0 + yy + i) * KK + r0 + xx] = __float2bfloat16(tile[xx][yy + i]);
    } else {
        const int idx = (blk - 1536) * 256 + tid;         // one thread per 8 elems
        const int e = idx * 8;
        const int m = e >> 9;                             // 0..2047 = c*256+b
        const int kk = e & 511;
        const int bb = m & 255, c = m >> 8;
        const float* src = x + (long)bb * (192 * 512) + (long)(c * 24 + 23) * 512 + kk;
        float4 v0 = *(const float4*)src;
        float4 v1 = *(const float4*)(src + 4);
        __hip_bfloat16* dst = Xb + (long)m * 512 + kk;
        dst[0] = __float2bfloat16(v0.x);
        dst[1] = __float2bfloat16(v0.y);
        dst[2] = __float2bfloat16(v0.z);
        dst[3] = __float2bfloat16(v0.w);
        dst[4] = __float2bfloat16(v1.x);
        dst[5] = __float2bfloat16(v1.y);
        dst[6] = __float2bfloat16(v1.z);
        dst[7] = __float2bfloat16(v1.w);
    }
}

// MX = A @ Kt^T + bias:  A[2048][512] bf16, Kt[1536][512] bf16 (=W^T), out f32.
__global__ __launch_bounds__(256)
void gemm_mx(const __hip_bfloat16* __restrict__ A,
             const __hip_bfloat16* __restrict__ Bt,
             const float* __restrict__ bias,
             float* __restrict__ C)
{
    const int tid = threadIdx.x;
    const int lane = tid & 63;
    const int wid = tid >> 6;                    // 0..3
    const int m0 = blockIdx.y * 64 + wid * 16;
    const int n0 = blockIdx.x * 64;
    const int lr = lane & 15;
    const int lk = (lane >> 4) * 8;

    const short8* ap = (const short8*)(A + (long)(m0 + lr) * KK + lk);
    const short8* bp = (const short8*)(Bt + (long)(n0 + lr) * KK + lk);

    f32x4 acc[4] = {{0.f,0.f,0.f,0.f},{0.f,0.f,0.f,0.f},
                    {0.f,0.f,0.f,0.f},{0.f,0.f,0.f,0.f}};
    #pragma unroll
    for (int k = 0; k < 16; ++k) {               // k0 = 32*k
        short8 a = ap[k * 4];
        #pragma unroll
        for (int t = 0; t < 4; ++t) {
            short8 b = bp[t * 1024 + k * 4];     // +16 rows = 16*512/8 short8
            acc[t] = __builtin_amdgcn_mfma_f32_16x16x32_bf16(a, b, acc[t], 0, 0, 0);
        }
    }
    const int row = (lane >> 4) * 4;
    #pragma unroll
    for (int t = 0; t < 4; ++t) {
        const int u = n0 + t * 16 + lr;
        const float bi = bias[u];
        #pragma unroll
        for (int q = 0; q < 4; ++q)
            C[(long)(m0 + row + q) * N3 + u] = acc[t][q] + bi;
    }
}

// Row-ownership 8-step chain. Grid = 16 WGs x 256 thr (4 waves). WG g owns h
// rows [g*16, g*16+16); wave w owns output cols [w*128, (w+1)*128) of every
// gate. No cross-WG data: h lives in LDS (bf16, swizzled) + f32 regs (hold).
__global__ __launch_bounds__(256, 1)
void gru_chain16(const __hip_bfloat16* __restrict__ Rt,   // [1536][512] bf16
                 const float* __restrict__ rbias,         // [1536]
                 const float* __restrict__ MX,            // [8][256][1536] f32
                 float* __restrict__ out)                 // [256][512] f32
{
    __shared__ char hls[16 * 1024];   // 16 rows x 512 bf16, XOR-swizzled
    const int tid = threadIdx.x;
    const int lane = tid & 63;
    const int w = tid >> 6;           // wave -> cols w*128..
    const int g = blockIdx.x;         // rows g*16..
    const int lr = lane & 15;
    const int hi = lane >> 4;         // 0..3
    const int u0 = w * 128;

    // rbias fragments (constant across steps): rb[gate][tile]
    float rb[3][8];
    #pragma unroll
    for (int gt = 0; gt < 3; ++gt)
        #pragma unroll
        for (int t = 0; t < 8; ++t)
            rb[gt][t] = rbias[gt * 512 + u0 + t * 16 + lr];

    // hold: this thread's own h patch (D-layout), f32, step-invariant position
    float hold[8][4];
    #pragma unroll
    for (int t = 0; t < 8; ++t)
        #pragma unroll
        for (int q = 0; q < 4; ++q) hold[t][q] = 0.0f;

    #pragma unroll 1
    for (int c = 0; c < 8; ++c) {
        const float* MXc = MX + (long)c * BB * N3;

        f32x4 acc[3][8];
        #pragma unroll
        for (int gt = 0; gt < 3; ++gt)
            #pragma unroll
            for (int t = 0; t < 8; ++t) acc[gt][t] = {0.f, 0.f, 0.f, 0.f};

        // A-fragments from LDS (old h), swizzled read: row lr, chunk kk*4+hi
        short8 Afr[16];
        if (c > 0) {
            #pragma unroll
            for (int kk = 0; kk < 16; ++kk) {
                const int byo = lr * 1024 + (((kk * 4 + hi) * 16) ^ ((lr & 7) << 4));
                Afr[kk] = *(const short8*)(hls + byo);
            }
        }

        // Hoist MX loads (global, independent of LDS/MFMA): mxv[gate][t][q]
        float mxv[3][8][4];
        #pragma unroll
        for (int t = 0; t < 8; ++t)
            #pragma unroll
            for (int q = 0; q < 4; ++q) {
                const float* p = MXc + (long)(g * 16 + hi * 4 + q) * N3
                               + u0 + t * 16 + lr;
                mxv[0][t][q] = p[0];
                mxv[1][t][q] = p[UU];
                mxv[2][t][q] = p[2 * UU];
            }

        __syncthreads();   // (A) all waves' A-reads complete -> writes allowed

        if (c > 0) {
            #pragma unroll
            for (int gt = 0; gt < 3; ++gt)
                #pragma unroll
                for (int tp = 0; tp < 4; ++tp) {      // tile pairs: dep-dist 2
                    const int t0 = tp * 2;
                    const short8* bp0 = (const short8*)(Rt
                        + (long)(gt * 512 + u0 + t0 * 16 + lr) * KK + hi * 8);
                    const short8* bp1 = (const short8*)(Rt
                        + (long)(gt * 512 + u0 + (t0 + 1) * 16 + lr) * KK + hi * 8);
                    short8 B0[16], B1[16];
                    #pragma unroll
                    for (int kk = 0; kk < 16; ++kk) {
                        B0[kk] = bp0[kk * 4];
                        B1[kk] = bp1[kk * 4];
                    }
                    #pragma unroll
                    for (int kk = 0; kk < 16; ++kk) {
                        acc[gt][t0] = __builtin_amdgcn_mfma_f32_16x16x32_bf16(
                            Afr[kk], B0[kk], acc[gt][t0], 0, 0, 0);
                        acc[gt][t0 + 1] = __builtin_amdgcn_mfma_f32_16x16x32_bf16(
                            Afr[kk], B1[kk], acc[gt][t0 + 1], 0, 0, 0);
                    }
                }
        }

        // GRU elementwise update on own patch; write new h (bf16) to LDS.
        #pragma unroll
        for (int t = 0; t < 8; ++t)
            #pragma unroll
            for (int q = 0; q < 4; ++q) {
                const float z = sigmoidf_(mxv[0][t][q] + acc[0][t][q] + rb[0][t]);
                const float r = sigmoidf_(mxv[1][t][q] + acc[1][t][q] + rb[1][t]);
                const float cand = mxv[2][t][q] + r * (acc[2][t][q] + rb[2][t]);
                const float hh = fmaxf(cand, 0.0f);              // relu
                const float hn = z * hold[t][q] + (1.0f - z) * hh;
                hold[t][q] = hn;
                const int rr = hi * 4 + q;
                if (c < 7) {
                    const int off = (u0 + t * 16 + lr) * 2;
                    *(__hip_bfloat16*)(hls + rr * 1024 + (off ^ ((rr & 7) << 4)))
                        = __float2bfloat16(hn);
                } else {
                    out[(long)(g * 16 + rr) * UU + u0 + t * 16 + lr] = hn;
                }
            }

        __syncthreads();   // (B) writes visible before next step's reads
    }
}

extern "C" void kernel_launch(void* const* d_in, const int* in_sizes, int n_in,
                              void* d_out, int out_size, void* d_ws, size_t ws_size,
                              hipStream_t stream)
{
    const float* x     = (const float*)d_in[0];   // [256,192,512]
    const float* ker   = (const float*)d_in[1];   // [512,1536]
    const float* rker  = (const float*)d_in[2];   // [512,1536]
    const float* ibias = (const float*)d_in[3];   // [1536]
    const float* rbias = (const float*)d_in[4];   // [1536]
    float* out = (float*)d_out;                   // [256,512]

    char* ws = (char*)d_ws;
    float*          MX   = (float*)ws;                            // 12,582,912 B
    __hip_bfloat16* Xb   = (__hip_bfloat16*)(ws + 12582912);      //  2,097,152 B
    __hip_bfloat16* Kt   = (__hip_bfloat16*)(ws + 14680064);      //  1,572,864 B
    __hip_bfloat16* Rt   = (__hip_bfloat16*)(ws + 16252928);      //  1,572,864 B

    // Node 1: fused prologue (2 transposes + x gather/convert)
    prologue<<<2048, 256, 0, stream>>>(ker, rker, x, Kt, Rt, Xb);

    // Node 2: MX = Xsel @ kernel + input_bias
    gemm_mx<<<dim3(N3 / 64, 2048 / 64), 256, 0, stream>>>(Xb, Kt, ibias, MX);

    // Node 3: all 8 GRU steps, 16 independent row-owning WGs, no cross-WG sync
    gru_chain16<<<16, 256, 0, stream>>>(Rt, rbias, MX, out);
}

// Round 11
// 555.787 us; speedup vs baseline: 1.0437x; 1.0437x over previous
//
#include <hip/hip_runtime.h>
#include <hip/hip_bf16.h>
#include <math.h>

// SkipGRU on MI355X, round 11: row-ownership chain, register-budget fixed.
// r10 post-mortem: VGPR_Count=256 (ceiling) + 10.7MB scratch writes = the
// 577us was pure spill traffic; prologue+gemm+overhead was only ~2us.
// Fix: 512-thread WGs (8 waves, 64 cols/wave) -> per-wave live set ~190 VGPR
// + 48 AGPR acc (fits 2 waves/SIMD, no spill); MX loads inline in epilogue
// (no 96-reg hoist); single-tile B streaming.
//
// Only chain j=23 contributes to outputs[:, -1, :] (t=191 = chunk 7 lane 23):
// 8 sequential GRU steps over x[:, c*24+23, :], h[256,512]. Each WG owns 16
// complete h rows -> zero cross-WG coupling, only __syncthreads between steps.
//
// mfma_f32_16x16x32_bf16 layouts (learn_hip m89-verified, r4-r10 validated):
//   A: lane l holds A[l&15][(l>>4)*8 + j]
//   B: lane l holds B[(l>>4)*8 + j][l&15]  (B^T row-major -> contiguous load)
//   D: lane l reg q -> row (l>>4)*4+q, col l&15
//
// h LDS tile [16 rows][512 bf16] = 16KB, XOR swizzle byte-off ^= (row&7)<<4
// on write AND read (bijective per row; verified numerically in r10).

typedef float f32x4 __attribute__((ext_vector_type(4)));
typedef short short8 __attribute__((ext_vector_type(8)));

#define BB 256
#define UU 512
#define KK 512
#define N3 1536

__device__ __forceinline__ float sigmoidf_(float s) {
    return 1.0f / (1.0f + __expf(-s));
}

// Fused prologue: blocks [0,768) transpose ker, [768,1536) transpose rker,
// [1536,2048) gather+convert x. All 256-thread blocks, branch block-uniform.
__global__ __launch_bounds__(256)
void prologue(const float* __restrict__ ker, const float* __restrict__ rker,
              const float* __restrict__ x,
              __hip_bfloat16* __restrict__ Kt, __hip_bfloat16* __restrict__ Rtb,
              __hip_bfloat16* __restrict__ Xb)
{
    __shared__ float tile[32][33];
    const int blk = blockIdx.x;
    const int tid = threadIdx.x;
    if (blk < 1536) {
        const float* W = (blk < 768) ? ker : rker;
        __hip_bfloat16* Wt = (blk < 768) ? Kt : Rtb;
        const int b = (blk < 768) ? blk : blk - 768;
        const int xx = tid & 31, yy = tid >> 5;           // (32, 8)
        const int c0 = (b % 48) * 32;                     // C = 1536
        const int r0 = (b / 48) * 32;                     // R = 512
        #pragma unroll
        for (int i = 0; i < 32; i += 8)
            tile[yy + i][xx] = W[(long)(r0 + yy + i) * N3 + c0 + xx];
        __syncthreads();
        #pragma unroll
        for (int i = 0; i < 32; i += 8)
            Wt[(long)(c0 + yy + i) * KK + r0 + xx] = __float2bfloat16(tile[xx][yy + i]);
    } else {
        const int idx = (blk - 1536) * 256 + tid;         // one thread per 8 elems
        const int e = idx * 8;
        const int m = e >> 9;                             // 0..2047 = c*256+b
        const int kk = e & 511;
        const int bb = m & 255, c = m >> 8;
        const float* src = x + (long)bb * (192 * 512) + (long)(c * 24 + 23) * 512 + kk;
        float4 v0 = *(const float4*)src;
        float4 v1 = *(const float4*)(src + 4);
        __hip_bfloat16* dst = Xb + (long)m * 512 + kk;
        dst[0] = __float2bfloat16(v0.x);
        dst[1] = __float2bfloat16(v0.y);
        dst[2] = __float2bfloat16(v0.z);
        dst[3] = __float2bfloat16(v0.w);
        dst[4] = __float2bfloat16(v1.x);
        dst[5] = __float2bfloat16(v1.y);
        dst[6] = __float2bfloat16(v1.z);
        dst[7] = __float2bfloat16(v1.w);
    }
}

// MX = A @ Kt^T + bias:  A[2048][512] bf16, Kt[1536][512] bf16 (=W^T), out f32.
__global__ __launch_bounds__(256)
void gemm_mx(const __hip_bfloat16* __restrict__ A,
             const __hip_bfloat16* __restrict__ Bt,
             const float* __restrict__ bias,
             float* __restrict__ C)
{
    const int tid = threadIdx.x;
    const int lane = tid & 63;
    const int wid = tid >> 6;                    // 0..3
    const int m0 = blockIdx.y * 64 + wid * 16;
    const int n0 = blockIdx.x * 64;
    const int lr = lane & 15;
    const int lk = (lane >> 4) * 8;

    const short8* ap = (const short8*)(A + (long)(m0 + lr) * KK + lk);
    const short8* bp = (const short8*)(Bt + (long)(n0 + lr) * KK + lk);

    f32x4 acc[4] = {{0.f,0.f,0.f,0.f},{0.f,0.f,0.f,0.f},
                    {0.f,0.f,0.f,0.f},{0.f,0.f,0.f,0.f}};
    #pragma unroll
    for (int k = 0; k < 16; ++k) {               // k0 = 32*k
        short8 a = ap[k * 4];
        #pragma unroll
        for (int t = 0; t < 4; ++t) {
            short8 b = bp[t * 1024 + k * 4];     // +16 rows = 16*512/8 short8
            acc[t] = __builtin_amdgcn_mfma_f32_16x16x32_bf16(a, b, acc[t], 0, 0, 0);
        }
    }
    const int row = (lane >> 4) * 4;
    #pragma unroll
    for (int t = 0; t < 4; ++t) {
        const int u = n0 + t * 16 + lr;
        const float bi = bias[u];
        #pragma unroll
        for (int q = 0; q < 4; ++q)
            C[(long)(m0 + row + q) * N3 + u] = acc[t][q] + bi;
    }
}

// Row-ownership 8-step chain. Grid = 16 WGs x 512 thr (8 waves). WG g owns h
// rows [g*16, g*16+16); wave w owns output cols [w*64, (w+1)*64) of every
// gate. No cross-WG data; h lives in LDS (bf16, swizzled) + f32 regs (hold).
__global__ __launch_bounds__(512)
void gru_chain16(const __hip_bfloat16* __restrict__ Rt,   // [1536][512] bf16
                 const float* __restrict__ rbias,         // [1536]
                 const float* __restrict__ MX,            // [8][256][1536] f32
                 float* __restrict__ out)                 // [256][512] f32
{
    __shared__ char hls[16 * 1024];   // 16 rows x 512 bf16, XOR-swizzled
    const int tid = threadIdx.x;
    const int lane = tid & 63;
    const int w = tid >> 6;           // wave 0..7 -> cols w*64..
    const int g = blockIdx.x;         // rows g*16..
    const int lr = lane & 15;
    const int hi = lane >> 4;         // 0..3
    const int u0 = w * 64;

    // rbias fragments (constant across steps)
    float rb[3][4];
    #pragma unroll
    for (int gt = 0; gt < 3; ++gt)
        #pragma unroll
        for (int t = 0; t < 4; ++t)
            rb[gt][t] = rbias[gt * 512 + u0 + t * 16 + lr];

    // hold: this thread's own h patch (D-layout), f32, step-invariant position
    float hold[4][4];
    #pragma unroll
    for (int t = 0; t < 4; ++t)
        #pragma unroll
        for (int q = 0; q < 4; ++q) hold[t][q] = 0.0f;

    #pragma unroll 1
    for (int c = 0; c < 8; ++c) {
        const float* MXc = MX + (long)c * BB * N3;

        // A-fragments from LDS (previous h), swizzled read.
        short8 Afr[16];
        if (c > 0) {
            #pragma unroll
            for (int kk = 0; kk < 16; ++kk) {
                const int byo = lr * 1024 + ((kk * 64 + hi * 16) ^ ((lr & 7) << 4));
                Afr[kk] = *(const short8*)(hls + byo);
            }
        }

        __syncthreads();   // (A) all reads of h done -> writes allowed below

        f32x4 acc[3][4];
        #pragma unroll
        for (int gt = 0; gt < 3; ++gt)
            #pragma unroll
            for (int t = 0; t < 4; ++t) acc[gt][t] = {0.f, 0.f, 0.f, 0.f};

        if (c > 0) {
            #pragma unroll
            for (int gt = 0; gt < 3; ++gt)
                #pragma unroll
                for (int t = 0; t < 4; ++t) {
                    const short8* bp = (const short8*)(Rt
                        + (long)(gt * 512 + u0 + t * 16 + lr) * KK + hi * 8);
                    short8 B[16];
                    #pragma unroll
                    for (int kk = 0; kk < 16; ++kk) B[kk] = bp[kk * 4];
                    #pragma unroll
                    for (int kk = 0; kk < 16; ++kk)
                        acc[gt][t] = __builtin_amdgcn_mfma_f32_16x16x32_bf16(
                            Afr[kk], B[kk], acc[gt][t], 0, 0, 0);
                }
        }

        // GRU elementwise update on own patch; MX loads inline (no big hoist).
        #pragma unroll
        for (int t = 0; t < 4; ++t)
            #pragma unroll
            for (int q = 0; q < 4; ++q) {
                const int rr = hi * 4 + q;
                const float* p = MXc + (long)(g * 16 + rr) * N3 + u0 + t * 16 + lr;
                const float z = sigmoidf_(p[0]      + acc[0][t][q] + rb[0][t]);
                const float r = sigmoidf_(p[UU]     + acc[1][t][q] + rb[1][t]);
                const float cand = p[2 * UU] + r * (acc[2][t][q] + rb[2][t]);
                const float hh = fmaxf(cand, 0.0f);              // relu
                const float hn = z * hold[t][q] + (1.0f - z) * hh;
                hold[t][q] = hn;
                if (c < 7) {
                    const int off = (u0 + t * 16 + lr) * 2;
                    *(__hip_bfloat16*)(hls + rr * 1024 + (off ^ ((rr & 7) << 4)))
                        = __float2bfloat16(hn);
                } else {
                    out[(long)(g * 16 + rr) * UU + u0 + t * 16 + lr] = hn;
                }
            }

        __syncthreads();   // (B) writes visible before next step's reads
    }
}

extern "C" void kernel_launch(void* const* d_in, const int* in_sizes, int n_in,
                              void* d_out, int out_size, void* d_ws, size_t ws_size,
                              hipStream_t stream)
{
    const float* x     = (const float*)d_in[0];   // [256,192,512]
    const float* ker   = (const float*)d_in[1];   // [512,1536]
    const float* rker  = (const float*)d_in[2];   // [512,1536]
    const float* ibias = (const float*)d_in[3];   // [1536]
    const float* rbias = (const float*)d_in[4];   // [1536]
    float* out = (float*)d_out;                   // [256,512]

    char* ws = (char*)d_ws;
    float*          MX   = (float*)ws;                            // 12,582,912 B
    __hip_bfloat16* Xb   = (__hip_bfloat16*)(ws + 12582912);      //  2,097,152 B
    __hip_bfloat16* Kt   = (__hip_bfloat16*)(ws + 14680064);      //  1,572,864 B
    __hip_bfloat16* Rt   = (__hip_bfloat16*)(ws + 16252928);      //  1,572,864 B

    // Node 1: fused prologue (2 transposes + x gather/convert)
    prologue<<<2048, 256, 0, stream>>>(ker, rker, x, Kt, Rt, Xb);

    // Node 2: MX = Xsel @ kernel + input_bias
    gemm_mx<<<dim3(N3 / 64, 2048 / 64), 256, 0, stream>>>(Xb, Kt, ibias, MX);

    // Node 3: all 8 GRU steps, 16 independent row-owning WGs, no cross-WG sync
    gru_chain16<<<16, 512, 0, stream>>>(Rt, rbias, MX, out);
}

// Round 12
// 474.044 us; speedup vs baseline: 1.2237x; 1.1724x over previous
//
#include <hip/hip_runtime.h>
#include <hip/hip_bf16.h>
#include <math.h>

// SkipGRU on MI355X, round 12: row-ownership chain; ACTUALLY unlock the VGPR
// budget. r11 post-mortem: __launch_bounds__(512) without min-waves let the
// compiler cap at 128 VGPR (4 waves/EU target) vs ~224 live demand -> B-loads
// issued in starved batches, each tile paying ~10 serialized L2 latencies ->
// 77us/step. Fix: __launch_bounds__(512,2) (2 waves/EU = our natural 8-wave
// WG occupancy -> ~512-reg cap), A-frags via ds_read in the MFMA loop, MX
// loads hoisted to overlap the MFMA phase.
//
// Only chain j=23 contributes to outputs[:, -1, :] (t=191 = chunk 7 lane 23):
// 8 sequential GRU steps over x[:, c*24+23, :], h[256,512]. Each WG owns 16
// complete h rows -> zero cross-WG coupling, only __syncthreads between steps.
//
// mfma_f32_16x16x32_bf16 layouts (learn_hip m89-verified, r4-r11 validated):
//   A: lane l holds A[l&15][(l>>4)*8 + j]
//   B: lane l holds B[(l>>4)*8 + j][l&15]  (B^T row-major -> contiguous load)
//   D: lane l reg q -> row (l>>4)*4+q, col l&15
//
// h LDS tile [16 rows][512 bf16] = 16KB, XOR swizzle byte-off ^= (row&7)<<4
// on write AND read (bijective per row; verified numerically r10/r11).

typedef float f32x4 __attribute__((ext_vector_type(4)));
typedef short short8 __attribute__((ext_vector_type(8)));

#define BB 256
#define UU 512
#define KK 512
#define N3 1536

__device__ __forceinline__ float sigmoidf_(float s) {
    return 1.0f / (1.0f + __expf(-s));
}

// Fused prologue: blocks [0,768) transpose ker, [768,1536) transpose rker,
// [1536,2048) gather+convert x. All 256-thread blocks, branch block-uniform.
__global__ __launch_bounds__(256)
void prologue(const float* __restrict__ ker, const float* __restrict__ rker,
              const float* __restrict__ x,
              __hip_bfloat16* __restrict__ Kt, __hip_bfloat16* __restrict__ Rtb,
              __hip_bfloat16* __restrict__ Xb)
{
    __shared__ float tile[32][33];
    const int blk = blockIdx.x;
    const int tid = threadIdx.x;
    if (blk < 1536) {
        const float* W = (blk < 768) ? ker : rker;
        __hip_bfloat16* Wt = (blk < 768) ? Kt : Rtb;
        const int b = (blk < 768) ? blk : blk - 768;
        const int xx = tid & 31, yy = tid >> 5;           // (32, 8)
        const int c0 = (b % 48) * 32;                     // C = 1536
        const int r0 = (b / 48) * 32;                     // R = 512
        #pragma unroll
        for (int i = 0; i < 32; i += 8)
            tile[yy + i][xx] = W[(long)(r0 + yy + i) * N3 + c0 + xx];
        __syncthreads();
        #pragma unroll
        for (int i = 0; i < 32; i += 8)
            Wt[(long)(c0 + yy + i) * KK + r0 + xx] = __float2bfloat16(tile[xx][yy + i]);
    } else {
        const int idx = (blk - 1536) * 256 + tid;         // one thread per 8 elems
        const int e = idx * 8;
        const int m = e >> 9;                             // 0..2047 = c*256+b
        const int kk = e & 511;
        const int bb = m & 255, c = m >> 8;
        const float* src = x + (long)bb * (192 * 512) + (long)(c * 24 + 23) * 512 + kk;
        float4 v0 = *(const float4*)src;
        float4 v1 = *(const float4*)(src + 4);
        __hip_bfloat16* dst = Xb + (long)m * 512 + kk;
        dst[0] = __float2bfloat16(v0.x);
        dst[1] = __float2bfloat16(v0.y);
        dst[2] = __float2bfloat16(v0.z);
        dst[3] = __float2bfloat16(v0.w);
        dst[4] = __float2bfloat16(v1.x);
        dst[5] = __float2bfloat16(v1.y);
        dst[6] = __float2bfloat16(v1.z);
        dst[7] = __float2bfloat16(v1.w);
    }
}

// MX = A @ Kt^T + bias:  A[2048][512] bf16, Kt[1536][512] bf16 (=W^T), out f32.
__global__ __launch_bounds__(256)
void gemm_mx(const __hip_bfloat16* __restrict__ A,
             const __hip_bfloat16* __restrict__ Bt,
             const float* __restrict__ bias,
             float* __restrict__ C)
{
    const int tid = threadIdx.x;
    const int lane = tid & 63;
    const int wid = tid >> 6;                    // 0..3
    const int m0 = blockIdx.y * 64 + wid * 16;
    const int n0 = blockIdx.x * 64;
    const int lr = lane & 15;
    const int lk = (lane >> 4) * 8;

    const short8* ap = (const short8*)(A + (long)(m0 + lr) * KK + lk);
    const short8* bp = (const short8*)(Bt + (long)(n0 + lr) * KK + lk);

    f32x4 acc[4] = {{0.f,0.f,0.f,0.f},{0.f,0.f,0.f,0.f},
                    {0.f,0.f,0.f,0.f},{0.f,0.f,0.f,0.f}};
    #pragma unroll
    for (int k = 0; k < 16; ++k) {               // k0 = 32*k
        short8 a = ap[k * 4];
        #pragma unroll
        for (int t = 0; t < 4; ++t) {
            short8 b = bp[t * 1024 + k * 4];     // +16 rows = 16*512/8 short8
            acc[t] = __builtin_amdgcn_mfma_f32_16x16x32_bf16(a, b, acc[t], 0, 0, 0);
        }
    }
    const int row = (lane >> 4) * 4;
    #pragma unroll
    for (int t = 0; t < 4; ++t) {
        const int u = n0 + t * 16 + lr;
        const float bi = bias[u];
        #pragma unroll
        for (int q = 0; q < 4; ++q)
            C[(long)(m0 + row + q) * N3 + u] = acc[t][q] + bi;
    }
}

// Row-ownership 8-step chain. Grid = 16 WGs x 512 thr (8 waves, 2/SIMD). WG g
// owns h rows [g*16, g*16+16); wave w owns output cols [w*64, (w+1)*64) of
// every gate. h lives in LDS (bf16, swizzled) + f32 regs (hold).
__global__ __launch_bounds__(512, 2)
void gru_chain16(const __hip_bfloat16* __restrict__ Rt,   // [1536][512] bf16
                 const float* __restrict__ rbias,         // [1536]
                 const float* __restrict__ MX,            // [8][256][1536] f32
                 float* __restrict__ out)                 // [256][512] f32
{
    __shared__ char hls[16 * 1024];   // 16 rows x 512 bf16, XOR-swizzled
    const int tid = threadIdx.x;
    const int lane = tid & 63;
    const int w = tid >> 6;           // wave 0..7 -> cols w*64..
    const int g = blockIdx.x;         // rows g*16..
    const int lr = lane & 15;
    const int hi = lane >> 4;         // 0..3
    const int u0 = w * 64;

    // rbias fragments (constant across steps)
    float rb[3][4];
    #pragma unroll
    for (int gt = 0; gt < 3; ++gt)
        #pragma unroll
        for (int t = 0; t < 4; ++t)
            rb[gt][t] = rbias[gt * 512 + u0 + t * 16 + lr];

    // hold: this thread's own h patch (D-layout), f32, step-invariant position
    float hold[4][4];
    #pragma unroll
    for (int t = 0; t < 4; ++t)
        #pragma unroll
        for (int q = 0; q < 4; ++q) hold[t][q] = 0.0f;

    #pragma unroll 1
    for (int c = 0; c < 8; ++c) {
        const float* MXc = MX + (long)c * BB * N3;

        // Hoist MX loads: issued first, consumed after the MFMA phase ->
        // global latency hides under ~2300 MFMA-phase cycles.
        float mxv[3][4][4];
        #pragma unroll
        for (int t = 0; t < 4; ++t)
            #pragma unroll
            for (int q = 0; q < 4; ++q) {
                const float* p = MXc + (long)(g * 16 + hi * 4 + q) * N3
                               + u0 + t * 16 + lr;
                mxv[0][t][q] = p[0];
                mxv[1][t][q] = p[UU];
                mxv[2][t][q] = p[2 * UU];
            }

        f32x4 acc[3][4];
        #pragma unroll
        for (int gt = 0; gt < 3; ++gt)
            #pragma unroll
            for (int t = 0; t < 4; ++t) acc[gt][t] = {0.f, 0.f, 0.f, 0.f};

        if (c > 0) {
            #pragma unroll
            for (int gt = 0; gt < 3; ++gt)
                #pragma unroll
                for (int t = 0; t < 4; ++t) {
                    const short8* bp = (const short8*)(Rt
                        + (long)(gt * 512 + u0 + t * 16 + lr) * KK + hi * 8);
                    short8 B[16];
                    #pragma unroll
                    for (int kk = 0; kk < 16; ++kk) B[kk] = bp[kk * 4];
                    #pragma unroll
                    for (int kk = 0; kk < 16; ++kk) {
                        // A fragment from LDS (previous h), swizzled read; the
                        // same 16 addresses repeat across tiles -> compiler may
                        // CSE into regs (headroom exists at the 2-wave cap).
                        const short8 a = *(const short8*)(hls + lr * 1024
                            + ((kk * 64 + hi * 16) ^ ((lr & 7) << 4)));
                        acc[gt][t] = __builtin_amdgcn_mfma_f32_16x16x32_bf16(
                            a, B[kk], acc[gt][t], 0, 0, 0);
                    }
                }
        }

        __syncthreads();   // (A) all LDS reads of h_{c-1} done -> writes ok

        // GRU elementwise update on own patch; write new h (bf16) to LDS.
        #pragma unroll
        for (int t = 0; t < 4; ++t)
            #pragma unroll
            for (int q = 0; q < 4; ++q) {
                const int rr = hi * 4 + q;
                const float z = sigmoidf_(mxv[0][t][q] + acc[0][t][q] + rb[0][t]);
                const float r = sigmoidf_(mxv[1][t][q] + acc[1][t][q] + rb[1][t]);
                const float cand = mxv[2][t][q] + r * (acc[2][t][q] + rb[2][t]);
                const float hh = fmaxf(cand, 0.0f);              // relu
                const float hn = z * hold[t][q] + (1.0f - z) * hh;
                hold[t][q] = hn;
                if (c < 7) {
                    const int off = (u0 + t * 16 + lr) * 2;
                    *(__hip_bfloat16*)(hls + rr * 1024 + (off ^ ((rr & 7) << 4)))
                        = __float2bfloat16(hn);
                } else {
                    out[(long)(g * 16 + rr) * UU + u0 + t * 16 + lr] = hn;
                }
            }

        __syncthreads();   // (B) writes visible before next step's reads
    }
}

extern "C" void kernel_launch(void* const* d_in, const int* in_sizes, int n_in,
                              void* d_out, int out_size, void* d_ws, size_t ws_size,
                              hipStream_t stream)
{
    const float* x     = (const float*)d_in[0];   // [256,192,512]
    const float* ker   = (const float*)d_in[1];   // [512,1536]
    const float* rker  = (const float*)d_in[2];   // [512,1536]
    const float* ibias = (const float*)d_in[3];   // [1536]
    const float* rbias = (const float*)d_in[4];   // [1536]
    float* out = (float*)d_out;                   // [256,512]

    char* ws = (char*)d_ws;
    float*          MX   = (float*)ws;                            // 12,582,912 B
    __hip_bfloat16* Xb   = (__hip_bfloat16*)(ws + 12582912);      //  2,097,152 B
    __hip_bfloat16* Kt   = (__hip_bfloat16*)(ws + 14680064);      //  1,572,864 B
    __hip_bfloat16* Rt   = (__hip_bfloat16*)(ws + 16252928);      //  1,572,864 B

    // Node 1: fused prologue (2 transposes + x gather/convert)
    prologue<<<2048, 256, 0, stream>>>(ker, rker, x, Kt, Rt, Xb);

    // Node 2: MX = Xsel @ kernel + input_bias
    gemm_mx<<<dim3(N3 / 64, 2048 / 64), 256, 0, stream>>>(Xb, Kt, ibias, MX);

    // Node 3: all 8 GRU steps, 16 independent row-owning WGs, no cross-WG sync
    gru_chain16<<<16, 512, 0, stream>>>(Rt, rbias, MX, out);
}

// Round 13
// 109.767 us; speedup vs baseline: 5.2846x; 4.3186x over previous
//
#include <hip/hip_runtime.h>
#include <hip/hip_bf16.h>
#include <math.h>

// SkipGRU on MI355X, round 13: persistent chain with LDS-RESIDENT B.
// Unifying model from r8/r9/r12 timings: every global MFMA-fragment load was
// paying a full serialized L2 round-trip (~400cyc); 64 loads/step = ~11us/step
// across ALL structures. Fix: stage each WG's B-slice (96KB: 32 cols x 3 gates
// x 512 k bf16) into LDS ONCE via global_load_lds with pre-swizzled per-lane
// global source (m173), reuse across all 7 steps; batch the 16 A-loads into
// one latency via asm keep-alives; prefetch next-step MX before the barrier.
// Geometry: 8 row-groups x 16 col-WGs (group g = blockIdx&7 -> same XCD under
// round-robin; correctness from fences regardless). r8's relaxed group
// barrier (numerically proven), counters zeroed in the fused prologue node.
//
// Only chain j=23 contributes to outputs[:, -1, :] (t=191 = chunk 7 lane 23):
// 8 sequential GRU steps over x[:, c*24+23, :], h[256,512].
//
// mfma_f32_16x16x32_bf16 layouts (learn_hip m89-verified, r4-r12 validated):
//   A: lane l holds A[l&15][(l>>4)*8 + j]
//   B: lane l holds B[(l>>4)*8 + j][l&15]  (B^T row-major -> contiguous load)
//   D: lane l reg q -> row (l>>4)*4+q, col l&15
//
// B LDS slice [96 rows][512 k] bf16, row j = gate*32 + (col-n0). XOR swizzle
// byte-off ^= (j&7)<<4 applied on the GLOBAL SOURCE during staging (LDS dest
// linear, as global_load_lds requires) and on the ds_read address (involution).

typedef float f32x4 __attribute__((ext_vector_type(4)));
typedef short short8 __attribute__((ext_vector_type(8)));

#define BB 256
#define UU 512
#define KK 512
#define N3 1536
#define NWG 128   // 8 row-groups x 16 col-WGs, 1 WG/CU (96KB LDS) -> co-resident
#define GWG 16    // WGs per row-group (sync domain)

__device__ __forceinline__ float sigmoidf_(float s) {
    return 1.0f / (1.0f + __expf(-s));
}

// Fused prologue: blocks [0,768) transpose ker, [768,1536) transpose rker,
// [1536,2048) gather+convert x, [2048,2052) zero barrier counters.
__global__ __launch_bounds__(256)
void prologue(const float* __restrict__ ker, const float* __restrict__ rker,
              const float* __restrict__ x,
              __hip_bfloat16* __restrict__ Kt, __hip_bfloat16* __restrict__ Rtb,
              __hip_bfloat16* __restrict__ Xb, unsigned* __restrict__ bar)
{
    __shared__ float tile[32][33];
    const int blk = blockIdx.x;
    const int tid = threadIdx.x;
    if (blk < 1536) {
        const float* W = (blk < 768) ? ker : rker;
        __hip_bfloat16* Wt = (blk < 768) ? Kt : Rtb;
        const int b = (blk < 768) ? blk : blk - 768;
        const int xx = tid & 31, yy = tid >> 5;           // (32, 8)
        const int c0 = (b % 48) * 32;                     // C = 1536
        const int r0 = (b / 48) * 32;                     // R = 512
        #pragma unroll
        for (int i = 0; i < 32; i += 8)
            tile[yy + i][xx] = W[(long)(r0 + yy + i) * N3 + c0 + xx];
        __syncthreads();
        #pragma unroll
        for (int i = 0; i < 32; i += 8)
            Wt[(long)(c0 + yy + i) * KK + r0 + xx] = __float2bfloat16(tile[xx][yy + i]);
    } else if (blk < 2048) {
        const int idx = (blk - 1536) * 256 + tid;         // one thread per 8 elems
        const int e = idx * 8;
        const int m = e >> 9;                             // 0..2047 = c*256+b
        const int kk = e & 511;
        const int bb = m & 255, c = m >> 8;
        const float* src = x + (long)bb * (192 * 512) + (long)(c * 24 + 23) * 512 + kk;
        float4 v0 = *(const float4*)src;
        float4 v1 = *(const float4*)(src + 4);
        __hip_bfloat16* dst = Xb + (long)m * 512 + kk;
        dst[0] = __float2bfloat16(v0.x);
        dst[1] = __float2bfloat16(v0.y);
        dst[2] = __float2bfloat16(v0.z);
        dst[3] = __float2bfloat16(v0.w);
        dst[4] = __float2bfloat16(v1.x);
        dst[5] = __float2bfloat16(v1.y);
        dst[6] = __float2bfloat16(v1.z);
        dst[7] = __float2bfloat16(v1.w);
    } else {
        const int i = (blk - 2048) * 256 + tid;
        if (i < 7 * 8 * 16) bar[i] = 0u;
    }
}

// MX = A @ Kt^T + bias:  A[2048][512] bf16, Kt[1536][512] bf16 (=W^T), out f32.
__global__ __launch_bounds__(256)
void gemm_mx(const __hip_bfloat16* __restrict__ A,
             const __hip_bfloat16* __restrict__ Bt,
             const float* __restrict__ bias,
             float* __restrict__ C)
{
    const int tid = threadIdx.x;
    const int lane = tid & 63;
    const int wid = tid >> 6;                    // 0..3
    const int m0 = blockIdx.y * 64 + wid * 16;
    const int n0 = blockIdx.x * 64;
    const int lr = lane & 15;
    const int lk = (lane >> 4) * 8;

    const short8* ap = (const short8*)(A + (long)(m0 + lr) * KK + lk);
    const short8* bp = (const short8*)(Bt + (long)(n0 + lr) * KK + lk);

    f32x4 acc[4] = {{0.f,0.f,0.f,0.f},{0.f,0.f,0.f,0.f},
                    {0.f,0.f,0.f,0.f},{0.f,0.f,0.f,0.f}};
    #pragma unroll
    for (int k = 0; k < 16; ++k) {               // k0 = 32*k
        short8 a = ap[k * 4];
        #pragma unroll
        for (int t = 0; t < 4; ++t) {
            short8 b = bp[t * 1024 + k * 4];     // +16 rows = 16*512/8 short8
            acc[t] = __builtin_amdgcn_mfma_f32_16x16x32_bf16(a, b, acc[t], 0, 0, 0);
        }
    }
    const int row = (lane >> 4) * 4;
    #pragma unroll
    for (int t = 0; t < 4; ++t) {
        const int u = n0 + t * 16 + lr;
        const float bi = bias[u];
        #pragma unroll
        for (int q = 0; q < 4; ++q)
            C[(long)(m0 + row + q) * N3 + u] = acc[t][q] + bi;
    }
}

// Group barrier (16 WGs). Arrival: release fence + one RELAXED fetch_add.
// Wait: RELAXED load spin (one line, no invalidate storm) + s_sleep.
// Exit: one acquire fence. Proven numerically in r8.
__device__ __forceinline__ void group_sync_(unsigned* cnt)
{
    __syncthreads();
    if (threadIdx.x == 0) {
        __threadfence();   // release: h stores visible before arrival
        __hip_atomic_fetch_add(cnt, 1u, __ATOMIC_RELAXED,
                               __HIP_MEMORY_SCOPE_AGENT);
        while (__hip_atomic_load(cnt, __ATOMIC_RELAXED,
                                 __HIP_MEMORY_SCOPE_AGENT) < (unsigned)GWG)
            __builtin_amdgcn_s_sleep(4);
        __threadfence();   // acquire: see other WGs' h stores
    }
    __syncthreads();
}

// Persistent 8-step chain, LDS-resident B. 128 WGs x 256 thr (4 waves).
// WG (by=blockIdx&7, bx=blockIdx>>3): rows by*32..+32, cols bx*32..+32, all 3
// gates. Wave w=(wy,wx): 16x16 patch. B-slice staged to LDS once; A-fragments
// batched from the group's h buffer; h own-patch carried in f32 registers.
__global__ __launch_bounds__(256, 1)
void gru_chain(const __hip_bfloat16* __restrict__ Rt,   // [1536][512] bf16
               const float* __restrict__ rbias,         // [1536]
               const float* __restrict__ MX,            // [8][256][1536] f32
               __hip_bfloat16* __restrict__ hbA,
               __hip_bfloat16* __restrict__ hbB,
               float* __restrict__ out,                 // [256][512] f32
               unsigned* __restrict__ bar)
{
    __shared__ char Bls[96 * 1024];   // [96 rows][1024 B], source-swizzled
    const int tid = threadIdx.x;
    const int lane = tid & 63;
    const int w = tid >> 6;           // wave 0..3
    const int wy = w >> 1, wx = w & 1;
    const int by = blockIdx.x & 7;    // row-group (same XCD under RR dispatch)
    const int bx = blockIdx.x >> 3;   // col WG in group (0..15)
    const int lr = lane & 15;
    const int hi = lane >> 4;         // 0..3
    const int m0 = by * 32 + wy * 16;
    const int n0 = bx * 32;
    const int u  = n0 + wx * 16 + lr;

    // ---- Stage B-slice into LDS (once): 96 rows x 1024B; per iteration each
    // wave DMAs one full row; global source pre-swizzled so swizzled ds_reads
    // below recover the original bytes (LDS dest stays linear, per HW rule).
    {
        const char* RtB = (const char*)Rt;
        #pragma unroll
        for (int i = 0; i < 24; ++i) {
            const int j  = i * 4 + w;                 // slice row 0..95
            const int gt = j >> 5, cc = j & 31;       // gate, col-in-slice
            const int off = lane * 16;
            const long srcoff = (long)(gt * 512 + n0 + cc) * 1024
                              + (off ^ ((j & 7) << 4));
            __builtin_amdgcn_global_load_lds(
                (const __attribute__((address_space(1))) unsigned int*)(RtB + srcoff),
                (__attribute__((address_space(3))) unsigned int*)(Bls + (long)j * 1024),
                16, 0, 0);
        }
    }

    const float rbz = rbias[u];
    const float rbg = rbias[u + UU];
    const float rbh = rbias[u + 2 * UU];

    float hold[4] = {0.f, 0.f, 0.f, 0.f};

    // MX for step 0 (prefetched; subsequent steps prefetch before the barrier)
    float mxv[3][4];
    #pragma unroll
    for (int q = 0; q < 4; ++q) {
        const float* p = MX + (long)(m0 + hi * 4 + q) * N3 + u;
        mxv[0][q] = p[0];
        mxv[1][q] = p[UU];
        mxv[2][q] = p[2 * UU];
    }

    #pragma unroll 1
    for (int c = 0; c < 8; ++c) {
        const __hip_bfloat16* hb_in = (c & 1) ? hbB : hbA;
        __hip_bfloat16*       hb_o  = (c & 1) ? hbA : hbB;

        f32x4 acc[3] = {{0.f,0.f,0.f,0.f},{0.f,0.f,0.f,0.f},{0.f,0.f,0.f,0.f}};

        if (c > 0) {
            // Batched A-load: 16 independent 16B loads, forced to all issue
            // before the MFMA region (keep-alives) -> ONE L2 latency.
            const short8* ap = (const short8*)hb_in + (long)(m0 + lr) * 64 + hi;
            short8 A[16];
            #pragma unroll
            for (int kk = 0; kk < 16; ++kk) A[kk] = ap[kk * 4];
            #pragma unroll
            for (int kk = 0; kk < 16; ++kk)
                asm volatile("" : : "v"(A[kk]));

            #pragma unroll
            for (int kk = 0; kk < 16; ++kk) {
                #pragma unroll
                for (int gt = 0; gt < 3; ++gt) {
                    const short8 b = *(const short8*)(Bls
                        + (long)(gt * 32 + wx * 16 + lr) * 1024
                        + ((kk * 64 + hi * 16) ^ ((lr & 7) << 4)));
                    acc[gt] = __builtin_amdgcn_mfma_f32_16x16x32_bf16(
                        A[kk], b, acc[gt], 0, 0, 0);
                }
            }
        }

        // GRU elementwise update on own patch.
        #pragma unroll
        for (int q = 0; q < 4; ++q) {
            const int m = m0 + hi * 4 + q;
            const float z = sigmoidf_(mxv[0][q] + acc[0][q] + rbz);
            const float r = sigmoidf_(mxv[1][q] + acc[1][q] + rbg);
            const float cand = mxv[2][q] + r * (acc[2][q] + rbh);   // reset_after
            const float hh = fmaxf(cand, 0.0f);                     // relu
            const float hn = z * hold[q] + (1.0f - z) * hh;
            hold[q] = hn;
            if (c < 7) hb_o[(long)m * UU + u] = __float2bfloat16(hn);
            else       out[(long)m * UU + u] = hn;
        }

        if (c < 7) {
            // Prefetch next step's MX before the sync (h-independent).
            #pragma unroll
            for (int q = 0; q < 4; ++q) {
                const float* p = MX + (long)(c + 1) * BB * N3
                               + (long)(m0 + hi * 4 + q) * N3 + u;
                mxv[0][q] = p[0];
                mxv[1][q] = p[UU];
                mxv[2][q] = p[2 * UU];
            }
            group_sync_(&bar[(c * 8 + by) * 16]);
        }
    }
}

extern "C" void kernel_launch(void* const* d_in, const int* in_sizes, int n_in,
                              void* d_out, int out_size, void* d_ws, size_t ws_size,
                              hipStream_t stream)
{
    const float* x     = (const float*)d_in[0];   // [256,192,512]
    const float* ker   = (const float*)d_in[1];   // [512,1536]
    const float* rker  = (const float*)d_in[2];   // [512,1536]
    const float* ibias = (const float*)d_in[3];   // [1536]
    const float* rbias = (const float*)d_in[4];   // [1536]
    float* out = (float*)d_out;                   // [256,512]

    char* ws = (char*)d_ws;
    float*          MX   = (float*)ws;                            // 12,582,912 B
    __hip_bfloat16* Xb   = (__hip_bfloat16*)(ws + 12582912);      //  2,097,152 B
    __hip_bfloat16* Kt   = (__hip_bfloat16*)(ws + 14680064);      //  1,572,864 B
    __hip_bfloat16* Rt   = (__hip_bfloat16*)(ws + 16252928);      //  1,572,864 B
    __hip_bfloat16* hbA  = (__hip_bfloat16*)(ws + 17825792);      //    262,144 B
    __hip_bfloat16* hbB  = (__hip_bfloat16*)(ws + 18087936);      //    262,144 B
    unsigned*       bar  = (unsigned*)(ws + 18350080);            //      3,584 B

    // Node 1: fused prologue (transposes + x gather/convert + barrier zero)
    prologue<<<2052, 256, 0, stream>>>(ker, rker, x, Kt, Rt, Xb, bar);

    // Node 2: MX = Xsel @ kernel + input_bias
    gemm_mx<<<dim3(N3 / 64, 2048 / 64), 256, 0, stream>>>(Xb, Kt, ibias, MX);

    // Node 3: all 8 GRU steps; B LDS-resident; group-local sync only.
    gru_chain<<<NWG, 256, 0, stream>>>(Rt, rbias, MX, hbA, hbB, out, bar);
}

// Round 14
// 107.062 us; speedup vs baseline: 5.4181x; 1.0253x over previous
//
#include <hip/hip_runtime.h>
#include <hip/hip_bf16.h>
#include <math.h>

// SkipGRU on MI355X, round 14: multi-kernel graph + gate-sequenced fragment
// batching in gru_step.
// r13 lessons: (a) node overhead is ~0.5us (r10: total-chain=2us for 2 nodes
// incl. prologue+gemm!), so multi-kernel sync is cheaper than any measured
// cross-WG barrier (~8.6us/step, r6/r8/r13); (b) r9's preload failed because
// A[16]+B[3][16]=256 VGPR of fragments + overhead > the 256-VGPR architectural
// cap (unified file's other 256 are AGPR-only) -> allocator re-chunked loads
// into serialized small batches. Fix: sequence the 3 gate B-batches so only
// TWO are live at once: peak ~245 VGPR. One L2 latency per batch (3/step).
//
// Only chain j=23 contributes to outputs[:, -1, :] (t=191 = chunk 7 lane 23):
// 8 sequential GRU steps over x[:, c*24+23, :], h[256,512].
//
// mfma_f32_16x16x32_bf16 layouts (learn_hip m89-verified, r4-r13 validated):
//   A: lane l holds A[l&15][(l>>4)*8 + j]
//   B: lane l holds B[(l>>4)*8 + j][l&15]  (B^T row-major -> contiguous load)
//   D: lane l reg q -> row (l>>4)*4+q, col l&15

typedef float f32x4 __attribute__((ext_vector_type(4)));
typedef short short8 __attribute__((ext_vector_type(8)));

#define BB 256
#define UU 512
#define KK 512
#define N3 1536

__device__ __forceinline__ float sigmoidf_(float s) {
    return 1.0f / (1.0f + __expf(-s));
}

// Fused prologue: blocks [0,768) transpose ker, [768,1536) transpose rker,
// [1536,2048) gather+convert x. All 256-thread blocks, branch block-uniform.
__global__ __launch_bounds__(256)
void prologue(const float* __restrict__ ker, const float* __restrict__ rker,
              const float* __restrict__ x,
              __hip_bfloat16* __restrict__ Kt, __hip_bfloat16* __restrict__ Rtb,
              __hip_bfloat16* __restrict__ Xb)
{
    __shared__ float tile[32][33];
    const int blk = blockIdx.x;
    const int tid = threadIdx.x;
    if (blk < 1536) {
        const float* W = (blk < 768) ? ker : rker;
        __hip_bfloat16* Wt = (blk < 768) ? Kt : Rtb;
        const int b = (blk < 768) ? blk : blk - 768;
        const int xx = tid & 31, yy = tid >> 5;           // (32, 8)
        const int c0 = (b % 48) * 32;                     // C = 1536
        const int r0 = (b / 48) * 32;                     // R = 512
        #pragma unroll
        for (int i = 0; i < 32; i += 8)
            tile[yy + i][xx] = W[(long)(r0 + yy + i) * N3 + c0 + xx];
        __syncthreads();
        #pragma unroll
        for (int i = 0; i < 32; i += 8)
            Wt[(long)(c0 + yy + i) * KK + r0 + xx] = __float2bfloat16(tile[xx][yy + i]);
    } else {
        const int idx = (blk - 1536) * 256 + tid;         // one thread per 8 elems
        const int e = idx * 8;
        const int m = e >> 9;                             // 0..2047 = c*256+b
        const int kk = e & 511;
        const int bb = m & 255, c = m >> 8;
        const float* src = x + (long)bb * (192 * 512) + (long)(c * 24 + 23) * 512 + kk;
        float4 v0 = *(const float4*)src;
        float4 v1 = *(const float4*)(src + 4);
        __hip_bfloat16* dst = Xb + (long)m * 512 + kk;
        dst[0] = __float2bfloat16(v0.x);
        dst[1] = __float2bfloat16(v0.y);
        dst[2] = __float2bfloat16(v0.z);
        dst[3] = __float2bfloat16(v0.w);
        dst[4] = __float2bfloat16(v1.x);
        dst[5] = __float2bfloat16(v1.y);
        dst[6] = __float2bfloat16(v1.z);
        dst[7] = __float2bfloat16(v1.w);
    }
}

// MX = A @ Kt^T + bias:  A[2048][512] bf16, Kt[1536][512] bf16 (=W^T), out f32.
__global__ __launch_bounds__(256)
void gemm_mx(const __hip_bfloat16* __restrict__ A,
             const __hip_bfloat16* __restrict__ Bt,
             const float* __restrict__ bias,
             float* __restrict__ C)
{
    const int tid = threadIdx.x;
    const int lane = tid & 63;
    const int wid = tid >> 6;                    // 0..3
    const int m0 = blockIdx.y * 64 + wid * 16;
    const int n0 = blockIdx.x * 64;
    const int lr = lane & 15;
    const int lk = (lane >> 4) * 8;

    const short8* ap = (const short8*)(A + (long)(m0 + lr) * KK + lk);
    const short8* bp = (const short8*)(Bt + (long)(n0 + lr) * KK + lk);

    f32x4 acc[4] = {{0.f,0.f,0.f,0.f},{0.f,0.f,0.f,0.f},
                    {0.f,0.f,0.f,0.f},{0.f,0.f,0.f,0.f}};
    #pragma unroll
    for (int k = 0; k < 16; ++k) {               // k0 = 32*k
        short8 a = ap[k * 4];
        #pragma unroll
        for (int t = 0; t < 4; ++t) {
            short8 b = bp[t * 1024 + k * 4];     // +16 rows = 16*512/8 short8
            acc[t] = __builtin_amdgcn_mfma_f32_16x16x32_bf16(a, b, acc[t], 0, 0, 0);
        }
    }
    const int row = (lane >> 4) * 4;
    #pragma unroll
    for (int t = 0; t < 4; ++t) {
        const int u = n0 + t * 16 + lr;
        const float bi = bias[u];
        #pragma unroll
        for (int q = 0; q < 4; ++q)
            C[(long)(m0 + row + q) * N3 + u] = acc[t][q] + bi;
    }
}

// Step 0 (h==0): mi = rbias, so pure elementwise from MX chunk 0.
__global__ __launch_bounds__(256)
void gru_step0(const float* __restrict__ MX0,         // [256][1536] f32
               const float* __restrict__ rbias,       // [1536]
               float* __restrict__ hf_out,            // [256][512] f32
               __hip_bfloat16* __restrict__ hbf_out)  // [256][512] bf16
{
    const int idx = blockIdx.x * 256 + threadIdx.x;   // b*512 + u
    const int b = idx >> 9;
    const int u = idx & 511;
    const float* mx = MX0 + (long)b * N3;
    const float z = sigmoidf_(mx[u]          + rbias[u]);
    const float r = sigmoidf_(mx[u + UU]     + rbias[u + UU]);
    const float cand = mx[u + 2 * UU] + r * rbias[u + 2 * UU];
    const float hh = fmaxf(cand, 0.0f);
    const float hn = (1.0f - z) * hh;
    hf_out[idx] = hn;
    hbf_out[idx] = __float2bfloat16(hn);
}

// One fused GRU step. Wave owns one 16x16 (m,u) patch across all 3 gates.
// GATE-SEQUENCED batching: only two 16-frag B batches live at once ->
// peak ~245 VGPR (< 256 cap) -> each batch is one load-burst + one wait.
__global__ __launch_bounds__(256, 1)
void gru_step(const __hip_bfloat16* __restrict__ hbf,  // [256][512] bf16
              const float* __restrict__ hf,            // [256][512] f32
              const __hip_bfloat16* __restrict__ Rt,   // [1536][512] bf16 (R^T)
              const float* __restrict__ rbias,         // [1536]
              const float* __restrict__ MXc,           // [256][1536] f32
              float* __restrict__ hf_out,              // [256][512] f32
              __hip_bfloat16* __restrict__ hbf_out)    // [256][512] bf16
{
    const int tid = threadIdx.x;
    const int lane = tid & 63;
    const int wid = tid >> 6;
    const int wy = wid >> 1, wx = wid & 1;
    const int m0 = blockIdx.y * 32 + wy * 16;
    const int n0 = blockIdx.x * 32 + wx * 16;
    const int lr = lane & 15;
    const int lk = (lane >> 4) * 8;
    const int row = (lane >> 4) * 4;
    const int u = n0 + lr;

    const short8* ap = (const short8*)(hbf + (long)(m0 + lr) * KK + lk);
    const short8* bp = (const short8*)(Rt + (long)(n0 + lr) * KK + lk);

    // Batch 1: A + Bz (32 independent 16B loads -> one latency).
    short8 A[16];
    #pragma unroll
    for (int k = 0; k < 16; ++k) A[k] = ap[k * 4];
    short8 Bz[16];
    #pragma unroll
    for (int k = 0; k < 16; ++k) Bz[k] = bp[k * 4];

    // Scalar loads (consumed only in the epilogue; in flight under MFMAs).
    float mxz[4], mxr[4], mxh[4], hold[4];
    #pragma unroll
    for (int q = 0; q < 4; ++q) {
        const float* mx = MXc + (long)(m0 + row + q) * N3 + u;
        mxz[q] = mx[0];
        mxr[q] = mx[UU];
        mxh[q] = mx[2 * UU];
        hold[q] = hf[(long)(m0 + row + q) * UU + u];
    }
    const float rbz = rbias[u];
    const float rbr = rbias[u + UU];
    const float rbh = rbias[u + 2 * UU];

    // Batch 2 issue: Br (in flight during z-gate MFMAs).
    short8 Br[16];
    #pragma unroll
    for (int k = 0; k < 16; ++k) Br[k] = bp[32768 + k * 4];

    f32x4 az = {0.f,0.f,0.f,0.f};
    #pragma unroll
    for (int k = 0; k < 16; ++k)
        az = __builtin_amdgcn_mfma_f32_16x16x32_bf16(A[k], Bz[k], az, 0, 0, 0);

    // Batch 3 issue: Bh (in flight during r-gate MFMAs). Bz now dead.
    short8 Bh[16];
    #pragma unroll
    for (int k = 0; k < 16; ++k) Bh[k] = bp[65536 + k * 4];

    f32x4 ar = {0.f,0.f,0.f,0.f};
    #pragma unroll
    for (int k = 0; k < 16; ++k)
        ar = __builtin_amdgcn_mfma_f32_16x16x32_bf16(A[k], Br[k], ar, 0, 0, 0);

    f32x4 ah = {0.f,0.f,0.f,0.f};
    #pragma unroll
    for (int k = 0; k < 16; ++k)
        ah = __builtin_amdgcn_mfma_f32_16x16x32_bf16(A[k], Bh[k], ah, 0, 0, 0);

    #pragma unroll
    for (int q = 0; q < 4; ++q) {
        const int m = m0 + row + q;
        const float z = sigmoidf_(mxz[q] + az[q] + rbz);
        const float r = sigmoidf_(mxr[q] + ar[q] + rbr);
        const float cand = mxh[q] + r * (ah[q] + rbh);   // reset_after
        const float hh = fmaxf(cand, 0.0f);              // relu
        const float hn = z * hold[q] + (1.0f - z) * hh;
        hf_out[(long)m * UU + u] = hn;
        hbf_out[(long)m * UU + u] = __float2bfloat16(hn);
    }
}

extern "C" void kernel_launch(void* const* d_in, const int* in_sizes, int n_in,
                              void* d_out, int out_size, void* d_ws, size_t ws_size,
                              hipStream_t stream)
{
    const float* x     = (const float*)d_in[0];   // [256,192,512]
    const float* ker   = (const float*)d_in[1];   // [512,1536]
    const float* rker  = (const float*)d_in[2];   // [512,1536]
    const float* ibias = (const float*)d_in[3];   // [1536]
    const float* rbias = (const float*)d_in[4];   // [1536]
    float* out = (float*)d_out;                   // [256,512]

    char* ws = (char*)d_ws;
    float*          MX   = (float*)ws;                            // 12,582,912 B
    __hip_bfloat16* Xb   = (__hip_bfloat16*)(ws + 12582912);      //  2,097,152 B
    __hip_bfloat16* Kt   = (__hip_bfloat16*)(ws + 14680064);      //  1,572,864 B
    __hip_bfloat16* Rt   = (__hip_bfloat16*)(ws + 16252928);      //  1,572,864 B
    float*          hf0  = (float*)(ws + 17825792);               //    524,288 B
    __hip_bfloat16* hbf0 = (__hip_bfloat16*)(ws + 18350080);      //    262,144 B
    float*          hf1  = (float*)(ws + 18612224);               //    524,288 B
    __hip_bfloat16* hbf1 = (__hip_bfloat16*)(ws + 19136512);      //    262,144 B

    // Node 1: fused prologue (2 transposes + x gather/convert)
    prologue<<<2048, 256, 0, stream>>>(ker, rker, x, Kt, Rt, Xb);

    // Node 2: MX = Xsel @ kernel + input_bias
    gemm_mx<<<dim3(N3 / 64, 2048 / 64), 256, 0, stream>>>(Xb, Kt, ibias, MX);

    // Node 3: step 0 (h0 == 0 -> elementwise), writes hf1/hbf1.
    gru_step0<<<dim3(BB * UU / 256), 256, 0, stream>>>(MX, rbias, hf1, hbf1);

    // Nodes 4-10: steps 1..7 (c odd reads hf1/hbf1)
    for (int c = 1; c < 8; ++c) {
        const __hip_bfloat16* hb_in = (c & 1) ? hbf1 : hbf0;
        const float*          hf_in = (c & 1) ? hf1 : hf0;
        float*          hf_o = (c == 7) ? out : ((c & 1) ? hf0 : hf1);
        __hip_bfloat16* hb_o = (c & 1) ? hbf0 : hbf1;
        gru_step<<<dim3(UU / 32, BB / 32), 256, 0, stream>>>(
            hb_in, hf_in, Rt, rbias, MX + (long)c * BB * N3, hf_o, hb_o);
    }
}